// Round 4
// baseline (179.880 us; speedup 1.0000x reference)
//
#include <hip/hip_runtime.h>
#include <math.h>

#define BB 32
#define NN 1000
#define CC 81
#define MAX_INST 100
#define MIN_CONF 0.7f
#define NMS_THRESH 0.3f
#define MCAP 1024     // per-batch candidate capacity in LDS (>= NN)
#define RCHUNK 64     // suppression-matrix rows per chunk (general path)
#define WMAX 16       // 64-bit words per keep row (1024/64)
#define PRODB (BB * NN / 8)   // 4000 producer blocks, 8 ROIs each

// Workspace layout:
//   sval : float [BB*NN]  @ 0x00000   publish flag: -score (valid) / -2.0 (invalid)
//   gcls : int   [BB*NN]  @ 0x20000   class id   (written only when valid)
//   gbox : float [BB*NN*4]@ 0x40000   decoded box (written only when valid)
//
// Single fused dispatch. Blocks 0..31 are per-batch consumers (NMS) that
// value-poll their 1000 flags; blocks 32..4031 are producers. Flag encoding is
// poison-robust: {-2.0} U [-1.0,-0.7] contains no repeated-byte float pattern.
// Publication: plain data stores -> __syncthreads (vmcnt drained) -> ONE
// __threadfence per block (cache-wide L2 writeback) -> relaxed agent-scope
// flag stores. Consumers read flags AND data with agent-scope atomic loads
// (bypass non-coherent local L2; served from LLC).

__device__ __forceinline__ bool flag_written(float w) {
  return (w == -2.0f) || (w >= -1.0f && w <= -0.7f);
}

__global__ __launch_bounds__(256) void detect_kernel(
    const float* __restrict__ rois,      // B,N,4
    const float* __restrict__ probs,     // B,N,C
    const float* __restrict__ deltas,    // B,N,C,4
    const float* __restrict__ std_dev,   // 4
    float* __restrict__ sval,
    int* __restrict__ gcls,
    float* __restrict__ gbox,            // 4 floats per ROI
    float* __restrict__ out)             // B,MAX_INST,6
{
  // ---------------- consumer LDS (allocated kernel-wide; ~45 KB) ----------------
  __shared__ float wsv[NN];        // raw flag words
  __shared__ int   lcnt;
  __shared__ float lscore[MCAP];   // append-order scores
  __shared__ int   lidx[MCAP];     // append-order original indices
  __shared__ float sy1[MCAP], sx1[MCAP], sy2[MCAP], sx2[MCAP]; // sorted boxes
  __shared__ int   scl[MCAP];      // sorted classes
  __shared__ float sscr[MCAP];     // sorted scores
  __shared__ unsigned long long rows[RCHUNK][WMAX];
  __shared__ unsigned long long keepw[WMAX];
  __shared__ float sflag[8];       // producer: per-half-wave flag values

  const int t = threadIdx.x;

  if (blockIdx.x >= BB) {
    // ================= producer block: 8 ROIs, one half-wave each =================
    const int wg = (blockIdx.x - BB) * 8 + (t >> 5);   // global ROI index < 32000
    const int hl = t & 31;

    const float* p = probs + (size_t)wg * CC;
    float v = p[hl];              // classes 0..31
    int   c = hl;
    float v2 = p[hl + 32];        // classes 32..63
    if (v2 > v) { v = v2; c = hl + 32; }            // strict >: lower class wins ties
    if (hl < CC - 64) {           // classes 64..80 (lanes 0..16)
      float v3 = p[hl + 64];
      if (v3 > v) { v = v3; c = hl + 64; }
    }
    // half-wave shuffle reduce; result lands in lane 0 of each 32-lane group
    for (int off = 16; off; off >>= 1) {
      float vo = __shfl_down(v, off);
      int   co = __shfl_down(c, off);
      if (vo > v || (vo == v && co < c)) { v = vo; c = co; }
    }

    if (hl == 0) {
      bool valid = (c > 0) && (v >= MIN_CONF);
      float flag = -2.0f;
      if (valid) {
        float4 dd = *(const float4*)(deltas + ((size_t)wg * CC + c) * 4);
        float4 r4 = *(const float4*)(rois + (size_t)wg * 4);
        float dy = dd.x * std_dev[0], dx = dd.y * std_dev[1];
        float dh = dd.z * std_dev[2], dw = dd.w * std_dev[3];
        float h = r4.z - r4.x, w = r4.w - r4.y;
        float cy = r4.x + 0.5f * h + dy * h;
        float cx = r4.y + 0.5f * w + dx * w;
        h *= expf(dh); w *= expf(dw);
        float y1 = cy - 0.5f * h, x1 = cx - 0.5f * w;
        float y2 = y1 + h,        x2 = x1 + w;
        y1 = fminf(fmaxf(y1, 0.f), 1.f); x1 = fminf(fmaxf(x1, 0.f), 1.f);
        y2 = fminf(fmaxf(y2, 0.f), 1.f); x2 = fminf(fmaxf(x2, 0.f), 1.f);
        gcls[wg] = c;
        float* gb = gbox + (size_t)wg * 4;
        gb[0] = y1; gb[1] = x1; gb[2] = y2; gb[3] = x2;
        flag = -v;                 // exact: sign flip only
      }
      sflag[t >> 5] = flag;
    }
    __syncthreads();               // all data stores drained to L2 (vmcnt 0)
    if (t < 8) {
      __threadfence();             // cache-wide L2 writeback -> LLC-visible
      __hip_atomic_store(&sval[(size_t)(blockIdx.x - BB) * 8 + t], sflag[t],
                         __ATOMIC_RELAXED, __HIP_MEMORY_SCOPE_AGENT);
    }
    return;
  }

  // ================= consumer block: batch b = blockIdx.x =================
  const int b = blockIdx.x;

  // zero this batch's output slice (harness poisons d_out)
  float4* ob4 = (float4*)(out + (size_t)b * MAX_INST * 6);
  for (int i = t; i < MAX_INST * 6 / 4; i += 256)
    ob4[i] = make_float4(0.f, 0.f, 0.f, 0.f);
  if (t == 0) lcnt = 0;

  // poll this batch's 1000 flags; thread t owns {t, t+256, t+512, t+768}
  const float* svb = sval + (size_t)b * NN;
  bool got0 = false, got1 = false, got2 = false, got3 = (t >= NN - 768);
  int rem = (t < NN - 768) ? 4 : 3;
  while (rem > 0) {
    if (!got0) {
      float w = __hip_atomic_load(&svb[t], __ATOMIC_RELAXED, __HIP_MEMORY_SCOPE_AGENT);
      if (flag_written(w)) { wsv[t] = w; got0 = true; --rem; }
    }
    if (!got1) {
      float w = __hip_atomic_load(&svb[t + 256], __ATOMIC_RELAXED, __HIP_MEMORY_SCOPE_AGENT);
      if (flag_written(w)) { wsv[t + 256] = w; got1 = true; --rem; }
    }
    if (!got2) {
      float w = __hip_atomic_load(&svb[t + 512], __ATOMIC_RELAXED, __HIP_MEMORY_SCOPE_AGENT);
      if (flag_written(w)) { wsv[t + 512] = w; got2 = true; --rem; }
    }
    if (!got3) {
      float w = __hip_atomic_load(&svb[t + 768], __ATOMIC_RELAXED, __HIP_MEMORY_SCOPE_AGENT);
      if (flag_written(w)) { wsv[t + 768] = w; got3 = true; --rem; }
    }
    if (rem > 0) __builtin_amdgcn_s_sleep(1);
  }
  __syncthreads();

  // compact valid entries into LDS (order nondeterministic; fixed by sort)
  #pragma unroll
  for (int k = 0; k < 4; ++k) {
    int idx = t + 256 * k;
    if (idx < NN) {
      float w = wsv[idx];
      if (w != -2.0f) { int q = atomicAdd(&lcnt, 1); lscore[q] = -w; lidx[q] = idx; }
    }
  }
  __syncthreads();

  const int M = lcnt;
  const size_t boff = (size_t)b * NN;

  // rank = stable-argsort position (score desc, orig idx asc); scatter sorted
  for (int e = t; e < M; e += 256) {
    float sc = lscore[e]; int oi = lidx[e];
    int r = 0;
    for (int j = 0; j < M; ++j) {
      float sj = lscore[j]; int ij = lidx[j];
      if (sj > sc || (sj == sc && ij < oi)) ++r;
    }
    const float* gb = gbox + (boff + oi) * 4;
    sy1[r] = __hip_atomic_load(&gb[0], __ATOMIC_RELAXED, __HIP_MEMORY_SCOPE_AGENT);
    sx1[r] = __hip_atomic_load(&gb[1], __ATOMIC_RELAXED, __HIP_MEMORY_SCOPE_AGENT);
    sy2[r] = __hip_atomic_load(&gb[2], __ATOMIC_RELAXED, __HIP_MEMORY_SCOPE_AGENT);
    sx2[r] = __hip_atomic_load(&gb[3], __ATOMIC_RELAXED, __HIP_MEMORY_SCOPE_AGENT);
    scl[r] = __hip_atomic_load(&gcls[boff + oi], __ATOMIC_RELAXED, __HIP_MEMORY_SCOPE_AGENT);
    sscr[r] = sc;
  }
  __syncthreads();

  if (M <= 64) {
    // -------- fast path: single-wave greedy NMS --------
    if (t < 64) {
      const int j = t;
      float jy1 = 0.f, jx1 = 0.f, jy2 = 0.f, jx2 = 0.f, aj = 0.f, jscr = 0.f;
      int jc = -1;
      if (j < M) {
        jy1 = sy1[j]; jx1 = sx1[j]; jy2 = sy2[j]; jx2 = sx2[j];
        jc = scl[j]; jscr = sscr[j];
        aj = (jy2 - jy1) * (jx2 - jx1);
      }
      unsigned long long keep = (M >= 64) ? ~0ULL : ((1ULL << M) - 1ULL);
      for (int i = 0; i < M; ++i) {
        if ((keep >> i) & 1ULL) {
          float iy1 = sy1[i], ix1 = sx1[i], iy2 = sy2[i], ix2 = sx2[i];
          int   ic  = scl[i];
          float ai  = (iy2 - iy1) * (ix2 - ix1);
          bool cond = false;
          if (j > i && j < M && jc == ic) {
            float iy = fmaxf(fminf(iy2, jy2) - fmaxf(iy1, jy1), 0.f);
            float ix = fmaxf(fminf(ix2, jx2) - fmaxf(ix1, jx1), 0.f);
            float inter = iy * ix;
            float uni = fmaxf(ai + aj - inter, 1e-8f);
            cond = (inter / uni) > NMS_THRESH;
          }
          keep &= ~__ballot(cond);
        }
      }
      if (j < M && ((keep >> j) & 1ULL)) {
        int slot = __popcll(keep & ((1ULL << j) - 1ULL));
        if (slot < MAX_INST) {
          float* o = out + ((size_t)b * MAX_INST + slot) * 6;
          o[0] = jy1; o[1] = jx1; o[2] = jy2; o[3] = jx2;
          o[4] = (float)jc; o[5] = jscr;
        }
      }
    }
    return;
  }

  // -------- general path: chunked suppression matrix (any M <= MCAP) --------
  const int W = (M + 63) >> 6;
  if (t < WMAX) {
    unsigned long long kw = 0ULL;
    int nb = M - t * 64;
    if (nb > 0) kw = (nb >= 64) ? ~0ULL : ((1ULL << nb) - 1ULL);
    keepw[t] = kw;
  }
  __syncthreads();

  const int wv = t >> 6, lane = t & 63;
  for (int c0 = 0; c0 < M; c0 += RCHUNK) {
    int R = min(RCHUNK, M - c0);
    for (int task = wv; task < R * W; task += 4) {
      int i = c0 + task / W;
      int w = task % W;
      int j = w * 64 + lane;
      bool cond = false;
      float iy1 = sy1[i], ix1 = sx1[i], iy2 = sy2[i], ix2 = sx2[i];
      int ic = scl[i];
      if (j < M && j > i && scl[j] == ic) {
        float jy1 = sy1[j], jx1 = sx1[j], jy2 = sy2[j], jx2 = sx2[j];
        float ai = (iy2 - iy1) * (ix2 - ix1);
        float aj = (jy2 - jy1) * (jx2 - jx1);
        float iy = fmaxf(fminf(iy2, jy2) - fmaxf(iy1, jy1), 0.f);
        float ix = fmaxf(fminf(ix2, jx2) - fmaxf(ix1, jx1), 0.f);
        float inter = iy * ix;
        float uni = fmaxf(ai + aj - inter, 1e-8f);
        cond = (inter / uni) > NMS_THRESH;
      }
      unsigned long long word = __ballot(cond);
      if (lane == 0) rows[task / W][w] = word;
    }
    __syncthreads();
    if (t < 64) {
      unsigned long long kw = (t < W) ? keepw[t] : 0ULL;
      for (int i = c0; i < c0 + R; ++i) {
        unsigned long long kwi = __shfl((long long)kw, i >> 6); // uniform lane
        if ((kwi >> (i & 63)) & 1ULL) {
          if (t < W) kw &= ~rows[i - c0][t];
        }
      }
      if (t < W) keepw[t] = kw;
    }
    __syncthreads();
  }

  for (int r = t; r < M; r += 256) {
    unsigned long long kwme = keepw[r >> 6];
    if ((kwme >> (r & 63)) & 1ULL) {
      int slot = 0;
      for (int w = 0; w < (r >> 6); ++w) slot += __popcll(keepw[w]);
      slot += __popcll(kwme & ((1ULL << (r & 63)) - 1ULL));
      if (slot < MAX_INST) {
        float* o = out + ((size_t)b * MAX_INST + slot) * 6;
        o[0] = sy1[r]; o[1] = sx1[r]; o[2] = sy2[r]; o[3] = sx2[r];
        o[4] = (float)scl[r]; o[5] = sscr[r];
      }
    }
  }
}

extern "C" void kernel_launch(void* const* d_in, const int* in_sizes, int n_in,
                              void* d_out, int out_size, void* d_ws, size_t ws_size,
                              hipStream_t stream) {
  const float* rois    = (const float*)d_in[0];
  const float* probs   = (const float*)d_in[1];
  const float* deltas  = (const float*)d_in[2];
  const float* std_dev = (const float*)d_in[3];
  float* out = (float*)d_out;

  float* sval = (float*)d_ws;                          // 128 KB
  int*   gcls = (int*)((char*)d_ws + 0x20000);         // 128 KB
  float* gbox = (float*)((char*)d_ws + 0x40000);       // 512 KB

  detect_kernel<<<PRODB + BB, 256, 0, stream>>>(rois, probs, deltas, std_dev,
                                                sval, gcls, gbox, out);
}

// Round 5
// 99.469 us; speedup vs baseline: 1.8084x; 1.8084x over previous
//
#include <hip/hip_runtime.h>
#include <math.h>

#define BB 32
#define NN 1000
#define CC 81
#define MAX_INST 100
#define MIN_CONF 0.7f
#define NMS_THRESH 0.3f
#define MCAP 1024     // per-batch candidate capacity in LDS (>= NN)
#define RCHUNK 192    // suppression-matrix rows per chunk (general path)
#define WMAX 16       // 64-bit words per keep row (1024/64)

// Workspace layout (ws is re-poisoned by harness every iteration; every word we
// read is rewritten every iteration):
//   sval : float [BB*NN]  @ 0x00000   score if valid else -1 (always written)
//   gcls : int   [BB*NN]  @ 0x20000   class id   (written only when valid)
//   gbox : float4[BB*NN]  @ 0x40000   decoded box (written only when valid)

// ---------------- Kernel A: one HALF-WAVE (32 lanes) per ROI ----------------
// Lane l covers classes {l, l+32, l+64(<81)}; 5-step shuffle reduce within the
// 32-lane group (first-occurrence argmax: lower class wins ties). Lane 0 of
// each group decodes/clips and writes the SoA record for its ROI.
__global__ __launch_bounds__(256) void roi_kernel(
    const float* __restrict__ rois,      // B,N,4
    const float* __restrict__ probs,     // B,N,C
    const float* __restrict__ deltas,    // B,N,C,4
    const float* __restrict__ std_dev,   // 4
    float* __restrict__ sval,
    int* __restrict__ gcls,
    float4* __restrict__ gbox)
{
  int wg = blockIdx.x * 8 + (threadIdx.x >> 5);   // ROI index (8 per block)
  if (wg >= BB * NN) return;
  int hl = threadIdx.x & 31;

  const float* p = probs + (size_t)wg * CC;
  float v = p[hl];              // classes 0..31
  int   c = hl;
  float v2 = p[hl + 32];        // classes 32..63
  if (v2 > v) { v = v2; c = hl + 32; }            // strict >: lower class wins ties
  if (hl < CC - 64) {           // classes 64..80 (lanes 0..16)
    float v3 = p[hl + 64];
    if (v3 > v) { v = v3; c = hl + 64; }
  }
  // reduce within the 32-lane half-wave; result lands in lane 0 of each group
  for (int off = 16; off; off >>= 1) {
    float vo = __shfl_down(v, off);
    int   co = __shfl_down(c, off);
    if (vo > v || (vo == v && co < c)) { v = vo; c = co; }
  }

  if (hl == 0) {
    bool valid = (c > 0) && (v >= MIN_CONF);
    sval[wg] = valid ? v : -1.0f;
    if (valid) {
      float4 dd = *(const float4*)(deltas + ((size_t)wg * CC + c) * 4);
      float4 r4 = *(const float4*)(rois + (size_t)wg * 4);
      float dy = dd.x * std_dev[0], dx = dd.y * std_dev[1];
      float dh = dd.z * std_dev[2], dw = dd.w * std_dev[3];
      float h = r4.z - r4.x, w = r4.w - r4.y;
      float cy = r4.x + 0.5f * h + dy * h;
      float cx = r4.y + 0.5f * w + dx * w;
      h *= expf(dh); w *= expf(dw);
      float y1 = cy - 0.5f * h, x1 = cx - 0.5f * w;
      float y2 = y1 + h,        x2 = x1 + w;
      y1 = fminf(fmaxf(y1, 0.f), 1.f); x1 = fminf(fmaxf(x1, 0.f), 1.f);
      y2 = fminf(fmaxf(y2, 0.f), 1.f); x2 = fminf(fmaxf(x2, 0.f), 1.f);
      gcls[wg] = c;
      gbox[wg] = make_float4(y1, x1, y2, x2);
    }
  }
}

// ------------- Kernel B: one 256-thread block per batch — compact+sort+NMS -------------
__global__ __launch_bounds__(256) void nms_kernel(
    const float* __restrict__ sval,
    const int* __restrict__ gcls,
    const float4* __restrict__ gbox,
    float* __restrict__ out)         // B,MAX_INST,6
{
  const int b = blockIdx.x, t = threadIdx.x;

  __shared__ int   lcnt;
  __shared__ float lscore[MCAP];   // append-order scores (LDS-atomic compacted)
  __shared__ int   lidx[MCAP];     // append-order original indices
  __shared__ float sy1[MCAP], sx1[MCAP], sy2[MCAP], sx2[MCAP]; // sorted boxes
  __shared__ int   scl[MCAP];      // sorted classes
  __shared__ float sscr[MCAP];     // sorted scores
  __shared__ unsigned long long rows[RCHUNK][WMAX];
  __shared__ unsigned long long keepw[WMAX];

  // zero this batch's output slice (harness poisons d_out)
  float4* ob4 = (float4*)(out + (size_t)b * MAX_INST * 6);
  for (int i = t; i < MAX_INST * 6 / 4; i += 256)
    ob4[i] = make_float4(0.f, 0.f, 0.f, 0.f);

  if (t == 0) lcnt = 0;
  __syncthreads();

  // compact valid records into LDS: coalesced float4 scan of the score array
  const float4* sv4 = (const float4*)(sval + (size_t)b * NN);   // 250 quads
  if (t < NN / 4) {
    float4 s4 = sv4[t];
    if (s4.x >= 0.f) { int q = atomicAdd(&lcnt, 1); lscore[q] = s4.x; lidx[q] = 4 * t + 0; }
    if (s4.y >= 0.f) { int q = atomicAdd(&lcnt, 1); lscore[q] = s4.y; lidx[q] = 4 * t + 1; }
    if (s4.z >= 0.f) { int q = atomicAdd(&lcnt, 1); lscore[q] = s4.z; lidx[q] = 4 * t + 2; }
    if (s4.w >= 0.f) { int q = atomicAdd(&lcnt, 1); lscore[q] = s4.w; lidx[q] = 4 * t + 3; }
  }
  __syncthreads();

  const int M = lcnt;
  const size_t boff = (size_t)b * NN;

  // rank = stable-argsort position (score desc, orig idx asc); scatter sorted
  for (int e = t; e < M; e += 256) {
    float sc = lscore[e]; int oi = lidx[e];
    int r = 0;
    for (int j = 0; j < M; ++j) {
      float sj = lscore[j]; int ij = lidx[j];
      if (sj > sc || (sj == sc && ij < oi)) ++r;
    }
    float4 a = gbox[boff + oi];
    sy1[r] = a.x; sx1[r] = a.y; sy2[r] = a.z; sx2[r] = a.w;
    scl[r] = gcls[boff + oi]; sscr[r] = sc;
  }
  __syncthreads();

  if (M <= 64) {
    // -------- fast path: single-wave greedy NMS, no rows matrix --------
    if (t < 64) {
      const int j = t;
      float jy1 = 0.f, jx1 = 0.f, jy2 = 0.f, jx2 = 0.f, aj = 0.f, jscr = 0.f;
      int jc = -1;
      if (j < M) {
        jy1 = sy1[j]; jx1 = sx1[j]; jy2 = sy2[j]; jx2 = sx2[j];
        jc = scl[j]; jscr = sscr[j];
        aj = (jy2 - jy1) * (jx2 - jx1);
      }
      unsigned long long keep = (M >= 64) ? ~0ULL : ((1ULL << M) - 1ULL);
      for (int i = 0; i < M; ++i) {
        if ((keep >> i) & 1ULL) {
          float iy1 = sy1[i], ix1 = sx1[i], iy2 = sy2[i], ix2 = sx2[i]; // LDS broadcast
          int   ic  = scl[i];
          float ai  = (iy2 - iy1) * (ix2 - ix1);
          bool cond = false;
          if (j > i && j < M && jc == ic) {
            float iy = fmaxf(fminf(iy2, jy2) - fmaxf(iy1, jy1), 0.f);
            float ix = fmaxf(fminf(ix2, jx2) - fmaxf(ix1, jx1), 0.f);
            float inter = iy * ix;
            float uni = fmaxf(ai + aj - inter, 1e-8f);
            cond = (inter / uni) > NMS_THRESH;
          }
          keep &= ~__ballot(cond);
        }
      }
      if (j < M && ((keep >> j) & 1ULL)) {
        int slot = __popcll(keep & ((1ULL << j) - 1ULL));
        if (slot < MAX_INST) {
          float* o = out + ((size_t)b * MAX_INST + slot) * 6;
          o[0] = jy1; o[1] = jx1; o[2] = jy2; o[3] = jx2;
          o[4] = (float)jc; o[5] = jscr;
        }
      }
    }
    return;
  }

  // -------- general path: chunked suppression matrix (any M <= MCAP) --------
  const int W = (M + 63) >> 6;
  if (t < WMAX) {
    unsigned long long kw = 0ULL;
    int nb = M - t * 64;
    if (nb > 0) kw = (nb >= 64) ? ~0ULL : ((1ULL << nb) - 1ULL);
    keepw[t] = kw;
  }
  __syncthreads();

  const int wv = t >> 6, lane = t & 63;
  for (int c0 = 0; c0 < M; c0 += RCHUNK) {
    int R = min(RCHUNK, M - c0);
    for (int task = wv; task < R * W; task += 4) {
      int i = c0 + task / W;
      int w = task % W;
      int j = w * 64 + lane;
      bool cond = false;
      float iy1 = sy1[i], ix1 = sx1[i], iy2 = sy2[i], ix2 = sx2[i];
      int ic = scl[i];
      if (j < M && j > i && scl[j] == ic) {
        float jy1 = sy1[j], jx1 = sx1[j], jy2 = sy2[j], jx2 = sx2[j];
        float ai = (iy2 - iy1) * (ix2 - ix1);
        float aj = (jy2 - jy1) * (jx2 - jx1);
        float iy = fmaxf(fminf(iy2, jy2) - fmaxf(iy1, jy1), 0.f);
        float ix = fmaxf(fminf(ix2, jx2) - fmaxf(ix1, jx1), 0.f);
        float inter = iy * ix;
        float uni = fmaxf(ai + aj - inter, 1e-8f);
        cond = (inter / uni) > NMS_THRESH;
      }
      unsigned long long word = __ballot(cond);
      if (lane == 0) rows[task / W][w] = word;
    }
    __syncthreads();
    if (t < 64) {
      unsigned long long kw = (t < W) ? keepw[t] : 0ULL;
      for (int i = c0; i < c0 + R; ++i) {
        unsigned long long kwi = __shfl((long long)kw, i >> 6); // uniform lane
        if ((kwi >> (i & 63)) & 1ULL) {
          if (t < W) kw &= ~rows[i - c0][t];
        }
      }
      if (t < W) keepw[t] = kw;
    }
    __syncthreads();
  }

  for (int r = t; r < M; r += 256) {
    unsigned long long kwme = keepw[r >> 6];
    if ((kwme >> (r & 63)) & 1ULL) {
      int slot = 0;
      for (int w = 0; w < (r >> 6); ++w) slot += __popcll(keepw[w]);
      slot += __popcll(kwme & ((1ULL << (r & 63)) - 1ULL));
      if (slot < MAX_INST) {
        float* o = out + ((size_t)b * MAX_INST + slot) * 6;
        o[0] = sy1[r]; o[1] = sx1[r]; o[2] = sy2[r]; o[3] = sx2[r];
        o[4] = (float)scl[r]; o[5] = sscr[r];
      }
    }
  }
}

extern "C" void kernel_launch(void* const* d_in, const int* in_sizes, int n_in,
                              void* d_out, int out_size, void* d_ws, size_t ws_size,
                              hipStream_t stream) {
  const float* rois    = (const float*)d_in[0];
  const float* probs   = (const float*)d_in[1];
  const float* deltas  = (const float*)d_in[2];
  const float* std_dev = (const float*)d_in[3];
  float* out = (float*)d_out;

  float*  sval = (float*)d_ws;                          // 128 KB
  int*    gcls = (int*)((char*)d_ws + 0x20000);         // 128 KB
  float4* gbox = (float4*)((char*)d_ws + 0x40000);      // 512 KB

  roi_kernel<<<(BB * NN + 7) / 8, 256, 0, stream>>>(rois, probs, deltas, std_dev,
                                                    sval, gcls, gbox);
  nms_kernel<<<BB, 256, 0, stream>>>(sval, gcls, gbox, out);
}